// Round 1
// baseline (870.076 us; speedup 1.0000x reference)
//
#include <hip/hip_runtime.h>
#include <hip/hip_bf16.h>
#include <math.h>

// Problem constants (fixed by setup_inputs)
#define BB 16
#define CC 192
#define TS 2048
#define TT 512
#define KK 384   // 2*CC

// d_out float offsets
#define OFF_PATH 0
#define OFF_DUR  (16777216)
#define OFF_LOGW (OFF_DUR + 8192)
#define OFF_MEXP (OFF_LOGW + 8192)
#define OFF_LEXP (OFF_MEXP + 6291456)
#define OFF_TMASK (OFF_LEXP + 6291456)
#define OFF_SMASK (OFF_TMASK + 8192)

#define NEGC (-1e9)

// ---------------------------------------------------------------------------
// prep: per (b,u): s = exp(-2 logs), Bmat rows {m*s, s}, avec = nc1+nc4,
// plus text_mask / spec_mask outputs.
__global__ __launch_bounds__(512) void vits_prep(
    const float* __restrict__ m_p, const float* __restrict__ logs_p,
    const int* __restrict__ spec_len, const int* __restrict__ text_len,
    float* __restrict__ Bmat, float* __restrict__ avec,
    float* __restrict__ tmask, float* __restrict__ smask)
{
    const int b = blockIdx.x;
    const int u = threadIdx.x;
    const float C0 = -0.91893853320467274178f; // -0.5*log(2*pi)
    float a_acc = 0.f;
    for (int c = 0; c < CC; ++c) {
        float lg = logs_p[((size_t)b*CC + c)*TT + u];
        float mm = m_p[((size_t)b*CC + c)*TT + u];
        float s  = expf(-2.f*lg);
        float ms = mm * s;
        Bmat[((size_t)b*KK + 2*c    )*TT + u] = ms;  // pairs with z      -> neg_cent3
        Bmat[((size_t)b*KK + 2*c + 1)*TT + u] = s;   // pairs with -.5z^2 -> neg_cent2
        a_acc += C0 - lg - 0.5f*mm*ms;               // nc1 + nc4 terms
    }
    avec[b*TT + u] = a_acc;
    tmask[b*TT + u] = (u < text_len[b]) ? 1.f : 0.f;
    for (int t = u; t < TS; t += TT)
        smask[b*TS + t] = (t < spec_len[b]) ? 1.f : 0.f;
}

// ---------------------------------------------------------------------------
// gemm: nc[b][t][u] = avec[b][u] + sum_k X[k][t] * Bmat[k][u]
// X[2c][t] = z[b][c][t], X[2c+1][t] = -0.5*z^2. 64x64 tile, 4x4 microtile.
__global__ __launch_bounds__(256) void vits_gemm(
    const float* __restrict__ z, const float* __restrict__ Bmat,
    const float* __restrict__ avec, float* __restrict__ out)
{
    const int b  = blockIdx.z;
    const int t0 = blockIdx.y * 64;
    const int u0 = blockIdx.x * 64;
    __shared__ float As[16][68];
    __shared__ float Bs[16][68];
    const int tid = threadIdx.x;
    const int tx = tid & 15, ty = tid >> 4;
    float acc[4][4] = {};
    const float* zb = z    + (size_t)b * CC * TS;
    const float* Bb = Bmat + (size_t)b * KK * TT;
    for (int kc = 0; kc < KK/16; ++kc) {
        {
            int c_l = tid >> 5;            // 0..7
            int t_l = (tid & 31) * 2;
            const float* zp = zb + (size_t)(kc*8 + c_l)*TS + t0 + t_l;
            float2 zv = *(const float2*)zp;
            float2 z1 = make_float2(zv.x, zv.y);
            float2 z2 = make_float2(-0.5f*zv.x*zv.x, -0.5f*zv.y*zv.y);
            *(float2*)&As[2*c_l  ][t_l] = z1;
            *(float2*)&As[2*c_l+1][t_l] = z2;
            int k_l = tid >> 4;            // 0..15
            int u_l = (tid & 15) * 4;
            const float* bp = Bb + (size_t)(kc*16 + k_l)*TT + u0 + u_l;
            *(float4*)&Bs[k_l][u_l] = *(const float4*)bp;
        }
        __syncthreads();
        #pragma unroll
        for (int kk = 0; kk < 16; ++kk) {
            float4 av = *(const float4*)&As[kk][ty*4];
            float4 bv = *(const float4*)&Bs[kk][tx*4];
            float aa[4] = {av.x, av.y, av.z, av.w};
            float bb[4] = {bv.x, bv.y, bv.z, bv.w};
            #pragma unroll
            for (int i = 0; i < 4; ++i)
                #pragma unroll
                for (int jj = 0; jj < 4; ++jj)
                    acc[i][jj] += aa[i]*bb[jj];
        }
        __syncthreads();
    }
    float4 a4 = *(const float4*)(avec + b*TT + u0 + tx*4);
    float ab[4] = {a4.x, a4.y, a4.z, a4.w};
    #pragma unroll
    for (int i = 0; i < 4; ++i) {
        float4 o;
        o.x = acc[i][0] + ab[0];
        o.y = acc[i][1] + ab[1];
        o.z = acc[i][2] + ab[2];
        o.w = acc[i][3] + ab[3];
        *(float4*)(out + ((size_t)b*TS + t0 + ty*4 + i)*TT + u0 + tx*4) = o;
    }
}

// ---------------------------------------------------------------------------
// dp: forward Viterbi (f64, one wave per batch, 8 j per lane) + backtrack.
// dirs bit-packed per j along t (32-t windows) in LDS (128 KB).
// Emits duration, logw, and jt[b][t] (chosen text index per frame; -1 if t>=SL).
__global__ __launch_bounds__(64) void vits_dp(
    const float* __restrict__ nc,
    const int* __restrict__ spec_len, const int* __restrict__ text_len,
    float* __restrict__ dur, float* __restrict__ logw, int* __restrict__ jt)
{
    __shared__ unsigned int dirs[TT][TS/32];   // [512][64] u32 = 128 KB
    __shared__ int Tr[TT + 1];
    const int lane = threadIdx.x;
    const int b = blockIdx.x;
    const int SL = spec_len[b], TL = text_len[b];

    double q[8];
    #pragma unroll
    for (int e = 0; e < 8; ++e) q[e] = NEGC;
    if (lane == 0) q[0] = 0.0;
    unsigned int bits[8] = {0,0,0,0,0,0,0,0};

    const float* ncb = nc + (size_t)b*TS*TT + lane*8;
    float4 f0 = *(const float4*)(ncb);
    float4 f1 = *(const float4*)(ncb + 4);

    for (int t = 0; t < SL; ++t) {
        int tn = (t + 1 < SL) ? (t + 1) : (SL - 1);
        float4 g0 = *(const float4*)(ncb + (size_t)tn*TT);
        float4 g1 = *(const float4*)(ncb + (size_t)tn*TT + 4);

        double up = __shfl_up(q[7], 1);
        if (lane == 0) up = NEGC;
        float f[8] = {f0.x,f0.y,f0.z,f0.w,f1.x,f1.y,f1.z,f1.w};
        double qn[8];
        #pragma unroll
        for (int e = 0; e < 8; ++e) {
            double qs = (e == 0) ? up : q[e-1];
            bool d = (qs >= q[e]);                 // ref: q_shift >= q
            bits[e] = (bits[e] << 1) | (unsigned)d;
            double m = d ? qs : q[e];
            qn[e] = (double)f[e] + m;
        }
        #pragma unroll
        for (int e = 0; e < 8; ++e) q[e] = qn[e];
        if ((t & 31) == 31) {
            int w = t >> 5;
            #pragma unroll
            for (int e = 0; e < 8; ++e) { dirs[lane*8+e][w] = bits[e]; bits[e] = 0; }
        }
        f0 = g0; f1 = g1;
    }
    if (SL & 31) {
        int w = SL >> 5, r = SL & 31;
        #pragma unroll
        for (int e = 0; e < 8; ++e) dirs[lane*8+e][w] = bits[e] << (32 - r);
    }
    __syncthreads();

    for (int i = lane; i <= TT; i += 64) Tr[i] = 0;
    __syncthreads();

    if (lane == 0) {
        Tr[TL] = SL;
        int j = TL - 1, tc = SL - 1;
        // Tr[j] = first frame aligned to text index j (transition time)
        while (j > 0 && tc >= 0) {
            int w = tc >> 5;
            int bcur = 31 - (tc & 31);
            unsigned int W = dirs[j][w] & (0xFFFFFFFFu << bcur);
            if (W) {
                int bp = __ffs(W) - 1;          // lowest set bit >= bcur
                int tp = (w << 5) + 31 - bp;    // = largest t' <= tc with d=1
                Tr[j] = tp;
                --j;
                tc = tp - 1;
            } else {
                if (w == 0) break;
                tc = (w << 5) - 1;
            }
        }
    }
    __syncthreads();

    for (int u = lane; u < TT; u += 64) {
        float dv = (u < TL) ? (float)(Tr[u+1] - Tr[u]) : 0.0f;
        dur[b*TT + u] = dv;
        logw[b*TT + u] = (u < TL) ? logf(dv + 1e-6f) : 0.0f;
    }
    // jt: range-fill [Tr[u], Tr[u+1]) -> u
    for (int u = 0; u < TL; ++u) {
        int t1 = Tr[u+1];
        for (int t = Tr[u] + lane; t < t1; t += 64) jt[b*TS + t] = u;
    }
    for (int t = SL + lane; t < TS; t += 64) jt[b*TS + t] = -1;
}

// ---------------------------------------------------------------------------
// path: path[b][t][u] = (u == jt[b][t]) ? 1 : 0   (float4-vectorized)
__global__ void vits_path(const int* __restrict__ jt, float4* __restrict__ path)
{
    int idx = blockIdx.x*blockDim.x + threadIdx.x;
    const int total = BB*TS*(TT/4);
    for (; idx < total; idx += gridDim.x*blockDim.x) {
        int u4 = idx & (TT/4 - 1);
        int bt = idx >> 7;
        int j = jt[bt];
        float4 v = make_float4(0.f,0.f,0.f,0.f);
        int r = j - (u4 << 2);
        if (r >= 0 && r < 4) ((float*)&v)[r] = 1.f;
        path[idx] = v;
    }
}

// ---------------------------------------------------------------------------
// m/logs expansion: out[b][c][t] = (jt>=0) ? src[b][c][jt] : 0
__global__ void vits_mlexp(const int* __restrict__ jt,
    const float* __restrict__ m_p, const float* __restrict__ logs_p,
    float4* __restrict__ mexp, float4* __restrict__ lexp)
{
    int idx = blockIdx.x*blockDim.x + threadIdx.x;
    const int total = BB*CC*(TS/4);
    for (; idx < total; idx += gridDim.x*blockDim.x) {
        int t4 = idx & (TS/4 - 1);
        int bc = idx >> 9;
        int b = bc / CC;
        int4 jv = *(const int4*)(jt + b*TS + (t4 << 2));
        const float* mrow = m_p    + (size_t)bc*TT;
        const float* lrow = logs_p + (size_t)bc*TT;
        float4 mv, lv;
        mv.x = (jv.x >= 0) ? mrow[jv.x] : 0.f;  lv.x = (jv.x >= 0) ? lrow[jv.x] : 0.f;
        mv.y = (jv.y >= 0) ? mrow[jv.y] : 0.f;  lv.y = (jv.y >= 0) ? lrow[jv.y] : 0.f;
        mv.z = (jv.z >= 0) ? mrow[jv.z] : 0.f;  lv.z = (jv.z >= 0) ? lrow[jv.z] : 0.f;
        mv.w = (jv.w >= 0) ? mrow[jv.w] : 0.f;  lv.w = (jv.w >= 0) ? lrow[jv.w] : 0.f;
        mexp[idx] = mv;
        lexp[idx] = lv;
    }
}

// ---------------------------------------------------------------------------
extern "C" void kernel_launch(void* const* d_in, const int* in_sizes, int n_in,
                              void* d_out, int out_size, void* d_ws, size_t ws_size,
                              hipStream_t stream) {
    const float* z_p      = (const float*)d_in[0];
    const float* m_p      = (const float*)d_in[1];
    const float* logs_p   = (const float*)d_in[2];
    const int*   spec_len = (const int*)d_in[3];
    const int*   text_len = (const int*)d_in[4];
    float* out = (float*)d_out;

    float* Bmat = (float*)d_ws;                  // [B][384][512] f32 = 12.6 MB
    float* avec = Bmat + (size_t)BB*KK*TT;       // [B][512]
    int*   jt   = (int*)(avec + BB*TT);          // [B][2048]

    float* path  = out + OFF_PATH;   // doubles as neg_cent staging
    float* dur   = out + OFF_DUR;
    float* logw  = out + OFF_LOGW;
    float* mexp  = out + OFF_MEXP;
    float* lexp  = out + OFF_LEXP;
    float* tmask = out + OFF_TMASK;
    float* smask = out + OFF_SMASK;

    vits_prep<<<BB, 512, 0, stream>>>(m_p, logs_p, spec_len, text_len,
                                      Bmat, avec, tmask, smask);
    vits_gemm<<<dim3(TT/64, TS/64, BB), 256, 0, stream>>>(z_p, Bmat, avec, path);
    vits_dp<<<BB, 64, 0, stream>>>(path, spec_len, text_len, dur, logw, jt);
    vits_path<<<2048, 256, 0, stream>>>(jt, (float4*)path);
    vits_mlexp<<<2048, 256, 0, stream>>>(jt, m_p, logs_p, (float4*)mexp, (float4*)lexp);
}

// Round 2
// 651.394 us; speedup vs baseline: 1.3357x; 1.3357x over previous
//
#include <hip/hip_runtime.h>
#include <hip/hip_bf16.h>
#include <math.h>

// Problem constants (fixed by setup_inputs)
#define BB 16
#define CC 192
#define TS 2048
#define TT 512
#define KK 384   // 2*CC

// d_out float offsets
#define OFF_PATH 0
#define OFF_DUR  (16777216)
#define OFF_LOGW (OFF_DUR + 8192)
#define OFF_MEXP (OFF_LOGW + 8192)
#define OFF_LEXP (OFF_MEXP + 6291456)
#define OFF_TMASK (OFF_LEXP + 6291456)
#define OFF_SMASK (OFF_TMASK + 8192)

#define NEGC (-1e9)

// ---------------------------------------------------------------------------
// prep: per (b,u): s = exp(-2 logs), Bmat rows {m*s, s}, avec = nc1+nc4,
// plus text_mask / spec_mask outputs.
__global__ __launch_bounds__(512) void vits_prep(
    const float* __restrict__ m_p, const float* __restrict__ logs_p,
    const int* __restrict__ spec_len, const int* __restrict__ text_len,
    float* __restrict__ Bmat, float* __restrict__ avec,
    float* __restrict__ tmask, float* __restrict__ smask)
{
    const int b = blockIdx.x;
    const int u = threadIdx.x;
    const float C0 = -0.91893853320467274178f; // -0.5*log(2*pi)
    float a_acc = 0.f;
    for (int c = 0; c < CC; ++c) {
        float lg = logs_p[((size_t)b*CC + c)*TT + u];
        float mm = m_p[((size_t)b*CC + c)*TT + u];
        float s  = expf(-2.f*lg);
        float ms = mm * s;
        Bmat[((size_t)b*KK + 2*c    )*TT + u] = ms;  // pairs with z      -> neg_cent3
        Bmat[((size_t)b*KK + 2*c + 1)*TT + u] = s;   // pairs with -.5z^2 -> neg_cent2
        a_acc += C0 - lg - 0.5f*mm*ms;               // nc1 + nc4 terms
    }
    avec[b*TT + u] = a_acc;
    tmask[b*TT + u] = (u < text_len[b]) ? 1.f : 0.f;
    for (int t = u; t < TS; t += TT)
        smask[b*TS + t] = (t < spec_len[b]) ? 1.f : 0.f;
}

// ---------------------------------------------------------------------------
// gemm: nc[b][t][u] = avec[b][u] + sum_k X[k][t] * Bmat[k][u]
// X[2c][t] = z[b][c][t], X[2c+1][t] = -0.5*z^2. 64x64 tile, 4x4 microtile.
__global__ __launch_bounds__(256) void vits_gemm(
    const float* __restrict__ z, const float* __restrict__ Bmat,
    const float* __restrict__ avec, float* __restrict__ out)
{
    const int b  = blockIdx.z;
    const int t0 = blockIdx.y * 64;
    const int u0 = blockIdx.x * 64;
    __shared__ float As[16][68];
    __shared__ float Bs[16][68];
    const int tid = threadIdx.x;
    const int tx = tid & 15, ty = tid >> 4;
    float acc[4][4] = {};
    const float* zb = z    + (size_t)b * CC * TS;
    const float* Bb = Bmat + (size_t)b * KK * TT;
    for (int kc = 0; kc < KK/16; ++kc) {
        {
            int c_l = tid >> 5;            // 0..7
            int t_l = (tid & 31) * 2;
            const float* zp = zb + (size_t)(kc*8 + c_l)*TS + t0 + t_l;
            float2 zv = *(const float2*)zp;
            float2 z1 = make_float2(zv.x, zv.y);
            float2 z2 = make_float2(-0.5f*zv.x*zv.x, -0.5f*zv.y*zv.y);
            *(float2*)&As[2*c_l  ][t_l] = z1;
            *(float2*)&As[2*c_l+1][t_l] = z2;
            int k_l = tid >> 4;            // 0..15
            int u_l = (tid & 15) * 4;
            const float* bp = Bb + (size_t)(kc*16 + k_l)*TT + u0 + u_l;
            *(float4*)&Bs[k_l][u_l] = *(const float4*)bp;
        }
        __syncthreads();
        #pragma unroll
        for (int kk = 0; kk < 16; ++kk) {
            float4 av = *(const float4*)&As[kk][ty*4];
            float4 bv = *(const float4*)&Bs[kk][tx*4];
            float aa[4] = {av.x, av.y, av.z, av.w};
            float bb[4] = {bv.x, bv.y, bv.z, bv.w};
            #pragma unroll
            for (int i = 0; i < 4; ++i)
                #pragma unroll
                for (int jj = 0; jj < 4; ++jj)
                    acc[i][jj] += aa[i]*bb[jj];
        }
        __syncthreads();
    }
    float4 a4 = *(const float4*)(avec + b*TT + u0 + tx*4);
    float ab[4] = {a4.x, a4.y, a4.z, a4.w};
    #pragma unroll
    for (int i = 0; i < 4; ++i) {
        float4 o;
        o.x = acc[i][0] + ab[0];
        o.y = acc[i][1] + ab[1];
        o.z = acc[i][2] + ab[2];
        o.w = acc[i][3] + ab[3];
        *(float4*)(out + ((size_t)b*TS + t0 + ty*4 + i)*TT + u0 + tx*4) = o;
    }
}

// ---------------------------------------------------------------------------
// dp: forward Viterbi (f64, one wave per batch, 8 j per lane) + backtrack.
// P-deep register prefetch pipeline hides global-load latency.
// dirs bit-packed per j along t (32-t windows) in LDS (128 KB).
#define PIPE 16
__global__ __launch_bounds__(64, 1) void vits_dp(
    const float* __restrict__ nc,
    const int* __restrict__ spec_len, const int* __restrict__ text_len,
    float* __restrict__ dur, float* __restrict__ logw, int* __restrict__ jt)
{
    __shared__ unsigned int dirs[TT][TS/32];   // [512][64] u32 = 128 KB
    __shared__ int Tr[TT + 1];
    const int lane = threadIdx.x;
    const int b = blockIdx.x;
    const int SL = spec_len[b], TL = text_len[b];

    double q[8];
    #pragma unroll
    for (int e = 0; e < 8; ++e) q[e] = NEGC;
    if (lane == 0) q[0] = 0.0;
    unsigned int bits[8] = {0,0,0,0,0,0,0,0};

    const float* ncb = nc + (size_t)b*TS*TT + lane*8;

    // register pipeline: rows t..t+PIPE-1 in flight
    float4 a0[PIPE], a1[PIPE];
    #pragma unroll
    for (int i = 0; i < PIPE; ++i) {
        a0[i] = *(const float4*)(ncb + (size_t)i*TT);
        a1[i] = *(const float4*)(ncb + (size_t)i*TT + 4);
    }

    for (int tb = 0; tb < SL; tb += PIPE) {
        #pragma unroll
        for (int i = 0; i < PIPE; ++i) {
            const int t = tb + i;
            if (t >= SL) break;
            float4 f0 = a0[i], f1 = a1[i];
            int rp = t + PIPE; if (rp > SL - 1) rp = SL - 1;
            a0[i] = *(const float4*)(ncb + (size_t)rp*TT);
            a1[i] = *(const float4*)(ncb + (size_t)rp*TT + 4);

            double up = __shfl_up(q[7], 1);
            if (lane == 0) up = NEGC;
            float f[8] = {f0.x,f0.y,f0.z,f0.w,f1.x,f1.y,f1.z,f1.w};
            #pragma unroll
            for (int e = 7; e >= 1; --e) {
                bool d = (q[e-1] >= q[e]);          // ref: q_shift >= q
                bits[e] = (bits[e] << 1) | (unsigned)d;
                q[e] = (double)f[e] + fmax(q[e-1], q[e]);
            }
            {
                bool d = (up >= q[0]);
                bits[0] = (bits[0] << 1) | (unsigned)d;
                q[0] = (double)f[0] + fmax(up, q[0]);
            }
            if ((t & 31) == 31) {
                int w = t >> 5;
                #pragma unroll
                for (int e = 0; e < 8; ++e) { dirs[lane*8+e][w] = bits[e]; bits[e] = 0; }
            }
        }
    }
    if (SL & 31) {
        int w = SL >> 5, r = SL & 31;
        #pragma unroll
        for (int e = 0; e < 8; ++e) dirs[lane*8+e][w] = bits[e] << (32 - r);
    }
    __syncthreads();

    for (int i = lane; i <= TT; i += 64) Tr[i] = 0;
    __syncthreads();

    if (lane == 0) {
        Tr[TL] = SL;
        int j = TL - 1, tc = SL - 1;
        // Tr[j] = first frame aligned to text index j (transition time)
        while (j > 0 && tc >= 0) {
            int w = tc >> 5;
            int bcur = 31 - (tc & 31);
            unsigned int W = dirs[j][w] & (0xFFFFFFFFu << bcur);
            if (W) {
                int bp = __ffs(W) - 1;          // lowest set bit >= bcur
                int tp = (w << 5) + 31 - bp;    // = largest t' <= tc with d=1
                Tr[j] = tp;
                --j;
                tc = tp - 1;
            } else {
                if (w == 0) break;
                tc = (w << 5) - 1;
            }
        }
    }
    __syncthreads();

    for (int u = lane; u < TT; u += 64) {
        float dv = (u < TL) ? (float)(Tr[u+1] - Tr[u]) : 0.0f;
        dur[b*TT + u] = dv;
        logw[b*TT + u] = (u < TL) ? logf(dv + 1e-6f) : 0.0f;
    }
    // jt: range-fill [Tr[u], Tr[u+1]) -> u
    for (int u = 0; u < TL; ++u) {
        int t1 = Tr[u+1];
        for (int t = Tr[u] + lane; t < t1; t += 64) jt[b*TS + t] = u;
    }
    for (int t = SL + lane; t < TS; t += 64) jt[b*TS + t] = -1;
}

// ---------------------------------------------------------------------------
// path: path[b][t][u] = (u == jt[b][t]) ? 1 : 0   (float4-vectorized)
__global__ void vits_path(const int* __restrict__ jt, float4* __restrict__ path)
{
    int idx = blockIdx.x*blockDim.x + threadIdx.x;
    const int total = BB*TS*(TT/4);
    for (; idx < total; idx += gridDim.x*blockDim.x) {
        int u4 = idx & (TT/4 - 1);
        int bt = idx >> 7;
        int j = jt[bt];
        float4 v = make_float4(0.f,0.f,0.f,0.f);
        int r = j - (u4 << 2);
        if (r >= 0 && r < 4) ((float*)&v)[r] = 1.f;
        path[idx] = v;
    }
}

// ---------------------------------------------------------------------------
// m/logs expansion: out[b][c][t] = (jt>=0) ? src[b][c][jt] : 0
__global__ void vits_mlexp(const int* __restrict__ jt,
    const float* __restrict__ m_p, const float* __restrict__ logs_p,
    float4* __restrict__ mexp, float4* __restrict__ lexp)
{
    int idx = blockIdx.x*blockDim.x + threadIdx.x;
    const int total = BB*CC*(TS/4);
    for (; idx < total; idx += gridDim.x*blockDim.x) {
        int t4 = idx & (TS/4 - 1);
        int bc = idx >> 9;
        int b = bc / CC;
        int4 jv = *(const int4*)(jt + b*TS + (t4 << 2));
        const float* mrow = m_p    + (size_t)bc*TT;
        const float* lrow = logs_p + (size_t)bc*TT;
        float4 mv, lv;
        mv.x = (jv.x >= 0) ? mrow[jv.x] : 0.f;  lv.x = (jv.x >= 0) ? lrow[jv.x] : 0.f;
        mv.y = (jv.y >= 0) ? mrow[jv.y] : 0.f;  lv.y = (jv.y >= 0) ? lrow[jv.y] : 0.f;
        mv.z = (jv.z >= 0) ? mrow[jv.z] : 0.f;  lv.z = (jv.z >= 0) ? lrow[jv.z] : 0.f;
        mv.w = (jv.w >= 0) ? mrow[jv.w] : 0.f;  lv.w = (jv.w >= 0) ? lrow[jv.w] : 0.f;
        mexp[idx] = mv;
        lexp[idx] = lv;
    }
}

// ---------------------------------------------------------------------------
extern "C" void kernel_launch(void* const* d_in, const int* in_sizes, int n_in,
                              void* d_out, int out_size, void* d_ws, size_t ws_size,
                              hipStream_t stream) {
    const float* z_p      = (const float*)d_in[0];
    const float* m_p      = (const float*)d_in[1];
    const float* logs_p   = (const float*)d_in[2];
    const int*   spec_len = (const int*)d_in[3];
    const int*   text_len = (const int*)d_in[4];
    float* out = (float*)d_out;

    float* Bmat = (float*)d_ws;                  // [B][384][512] f32 = 12.6 MB
    float* avec = Bmat + (size_t)BB*KK*TT;       // [B][512]
    int*   jt   = (int*)(avec + BB*TT);          // [B][2048]

    float* path  = out + OFF_PATH;   // doubles as neg_cent staging
    float* dur   = out + OFF_DUR;
    float* logw  = out + OFF_LOGW;
    float* mexp  = out + OFF_MEXP;
    float* lexp  = out + OFF_LEXP;
    float* tmask = out + OFF_TMASK;
    float* smask = out + OFF_SMASK;

    vits_prep<<<BB, 512, 0, stream>>>(m_p, logs_p, spec_len, text_len,
                                      Bmat, avec, tmask, smask);
    vits_gemm<<<dim3(TT/64, TS/64, BB), 256, 0, stream>>>(z_p, Bmat, avec, path);
    vits_dp<<<BB, 64, 0, stream>>>(path, spec_len, text_len, dur, logw, jt);
    vits_path<<<2048, 256, 0, stream>>>(jt, (float4*)path);
    vits_mlexp<<<2048, 256, 0, stream>>>(jt, m_p, logs_p, (float4*)mexp, (float4*)lexp);
}